// Round 4
// baseline (141.548 us; speedup 1.0000x reference)
//
#include <hip/hip_runtime.h>
#include <math.h>

#define DD 160
#define HH 160
#define WW 160
#define NB 2
#define NEL (NB*DD*HH*WW)   // 8,192,000 voxels

#define XT 32               // x outputs per block
#define YT 16               // y outputs per block
#define ZC 10               // z outputs per block (v11: 16->10, grid 1600)
#define NTHR 256
#define NZCH (DD/ZC)        // 16
#define GX (WW/XT)          // 5
#define GY (HH/YT)          // 10
#define NBLK (GX*GY*NB*NZCH)   // 1600 blocks x 4 waves = 6400 waves
#define NPART NBLK

#define HR 22               // halo rows (16 + 6)
#define NJOB (HR*8)         // 176 x-conv jobs (< NTHR)
#define CP 35               // c4 physical pitch in float4 (32 + swizzle)

typedef float v2f __attribute__((ext_vector_type(2)));

struct G7 { float g[7]; };

// Fully fused separable 3D SSIM, v11 = LDS-residency attack.
//  * v8-v10 POST-MORTEM: per-wave VALU issue ~820cy of a ~4500cy slice
//    wall; stall is NOT global-load latency (v10: 2-deep prefetch
//    neutral) and NOT grid supply (v9: 2x grid, occupancy still 34%).
//    Occupancy pinned at ~2.75 blocks/CU across all runs while LDS
//    nominally allows 6 -- suspect coarse LDS allocation granularity
//    (25KB/block rounding to ~40KB -> 4-block cap, ~2.75 after
//    ramp/drain). The one untested resource.
//  * v11: SINGLE 12.3KB c4 buffer (was 2x dbuf, 24.6KB) + second
//    __syncthreads after C for WAR protection. If LDS was the cap,
//    residency -> 5-6 blocks/CU and cross-block wave overlap hides the
//    extra barrier (that overlap is exactly what's missing at 2.75).
//  * ZC 16->10: grid 1600 (6.25 blocks/CU available) so residency can
//    actually rise; z-halo tax only +16% (v9's ZC=8 was +27%).
//  * prefetch back to v7's 1-deep (2-deep proven neutral, saves VGPR).
//  * frozen: XCD swizzle, v2f pk-fma, c4 swizzle, z-rings, epilogue.
__global__ __launch_bounds__(NTHR, 4) void ssim_fused(
        const float* __restrict__ p, const float* __restrict__ t,
        float* __restrict__ partial, G7 gw) {
    const int tid = threadIdx.x;
    const int tx  = tid & 31;            // x output column (phase C)
    const int tyo = tid >> 5;            // 0..7, owns y = 2tyo, 2tyo+1

    // XCD-aware work remap (bijection on [0,1600), 1600 % 8 == 0)
    const int flat = blockIdx.x;
    const int w = (flat & 7) * (NBLK / 8) + (flat >> 3);
    const int bx = w % GX;
    const int by = (w / GX) % GY;
    const int bz = w / (GX * GY);        // 0..31

    const int x0 = bx * XT;
    const int y0 = by * YT;
    const int n  = bz / NZCH;
    const int zs = (bz % NZCH) * ZC;

    __shared__ float4 c4[HR][CP];        // single buffer, 12,320 B

    // z rings: [y-out][slot], slot5 freshest
    v2f r01[2][6], r23[2][6];
#pragma unroll
    for (int yo = 0; yo < 2; ++yo)
#pragma unroll
        for (int j = 0; j < 6; ++j) {
            r01[yo][j] = (v2f)(0.f);
            r23[yo][j] = (v2f)(0.f);
        }

    const float C1v = 1e-4f, C2v = 9e-4f;
    float ssum = 0.f;
    const int hw = HH * WW;
    const float* pv = p + (size_t)n * DD * hw;
    const float* tv = t + (size_t)n * DD * hw;

    // phase-B job decode (tid < 176): row br, x-group bxg
    const int br = tid >> 3;             // 0..21
    const int bxg = tid & 7;             // 0..7
    const int bgy = y0 + br - 3;
    const bool browok = (unsigned)bgy < (unsigned)HH && tid < NJOB;
    const int cbase = x0 + 4 * bxg - 4;  // first loaded column (4-aligned)
    const int pcr = tx + (tx >> 3);      // C-phase swizzled column

    float4 pfa[3], pfb[3];
    auto prefetch = [&](int sx) {
#pragma unroll
        for (int q = 0; q < 3; ++q) {
            pfa[q] = make_float4(0.f, 0.f, 0.f, 0.f);
            pfb[q] = make_float4(0.f, 0.f, 0.f, 0.f);
        }
        if (browok && sx >= 0 && sx < DD && sx < zs + ZC + 3) {
            const float* prow = pv + (size_t)sx * hw + bgy * WW;
            const float* trow = tv + (size_t)sx * hw + bgy * WW;
#pragma unroll
            for (int q = 0; q < 3; ++q) {
                int c0 = cbase + 4 * q;
                if ((unsigned)c0 < (unsigned)WW) {
                    pfa[q] = *(const float4*)(prow + c0);
                    pfb[q] = *(const float4*)(trow + c0);
                }
            }
        }
    };

    prefetch(zs - 3);

    for (int s = zs - 3; s < zs + ZC + 3; ++s) {
        const bool valid = (s >= 0) && (s < DD);   // block-uniform

        if (valid) {
            // ---- B: x-conv from prefetched registers ----
            if (tid < NJOB) {
                v2f s01[4], s23[4];
#pragma unroll
                for (int e = 0; e < 4; ++e) { s01[e] = (v2f)(0.f); s23[e] = (v2f)(0.f); }
#pragma unroll
                for (int q = 0; q < 3; ++q) {
                    const float af[4] = {pfa[q].x, pfa[q].y, pfa[q].z, pfa[q].w};
                    const float bf[4] = {pfb[q].x, pfb[q].y, pfb[q].z, pfb[q].w};
#pragma unroll
                    for (int j = 0; j < 4; ++j) {
                        const int i = 4 * q + j;     // loaded position 0..11
                        v2f pt; pt[0] = af[j]; pt[1] = bf[j];
                        v2f ud; ud[0] = af[j] + bf[j]; ud[1] = af[j] - bf[j];
                        v2f qu = ud * ud;
#pragma unroll
                        for (int e = 0; e < 4; ++e) {
                            const int k = i - e - 1;  // tap index
                            if (k >= 0 && k < 7) {
                                s01[e] = gw.g[k] * pt + s01[e];
                                s23[e] = gw.g[k] * qu + s23[e];
                            }
                        }
                    }
                }
#pragma unroll
                for (int e = 0; e < 4; ++e) {
                    int c = 4 * bxg + e;
                    c4[br][c + (c >> 3)] =
                        make_float4(s01[e][0], s01[e][1], s23[e][0], s23[e][1]);
                }
            }
            __syncthreads();   // bar1: B-writes visible (block-uniform)
        }

        // ---- issue next slice's global loads NOW (overlap C + ring) ----
        prefetch(s + 1);

        v2f m01[2], m23[2];
#pragma unroll
        for (int yo = 0; yo < 2; ++yo) {
            m01[yo] = (v2f)(0.f);
            m23[yo] = (v2f)(0.f);
        }

        if (valid) {
            // ---- C: y-conv, stream 8 rows for both y-outputs ----
#pragma unroll
            for (int r8 = 0; r8 < 8; ++r8) {
                float4 v = c4[2 * tyo + r8][pcr];
                v2f v01; v01[0] = v.x; v01[1] = v.y;
                v2f v23; v23[0] = v.z; v23[1] = v.w;
                if (r8 < 7) {
                    float w2 = gw.g[r8];
                    m01[0] = w2 * v01 + m01[0];
                    m23[0] = w2 * v23 + m23[0];
                }
                if (r8 > 0) {
                    float w2 = gw.g[r8 - 1];
                    m01[1] = w2 * v01 + m01[1];
                    m23[1] = w2 * v23 + m23[1];
                }
            }
            __syncthreads();   // bar2: C-reads done -> next B may overwrite
        }

        // ---- z rings: consume slot0, shift+FMA, refill (registers only) ----
#pragma unroll
        for (int yo = 0; yo < 2; ++yo) {
            v2f v01 = m01[yo], v23 = m23[yo];
            v2f cons01 = gw.g[6] * v01 + r01[yo][0];
            v2f cons23 = gw.g[6] * v23 + r23[yo][0];
#pragma unroll
            for (int j = 0; j < 5; ++j) {
                r01[yo][j] = gw.g[5 - j] * v01 + r01[yo][j + 1];
                r23[yo][j] = gw.g[5 - j] * v23 + r23[yo][j + 1];
            }
            r01[yo][5] = gw.g[0] * v01;
            r23[yo][5] = gw.g[0] * v23;

            if (s >= zs + 3) {   // output z = s-3
                float mu1 = cons01[0], mu2 = cons01[1];
                float Eu  = cons23[0], Ew  = cons23[1];
                float mu12 = mu1 * mu2, mu1sq = mu1 * mu1, mu2sq = mu2 * mu2;
                float sumsq = 0.5f  * (Eu + Ew) - mu1sq - mu2sq; // s1+s2
                float s12   = 0.25f * (Eu - Ew) - mu12;          // sigma12
                float num = (2.f * mu12 + C1v) * (2.f * s12 + C2v);
                float den = (mu1sq + mu2sq + C1v) * (sumsq + C2v);
                ssum += num * __builtin_amdgcn_rcpf(den);
            }
        }
    }

    // ---- block reduction (4 waves) ----
#pragma unroll
    for (int off = 32; off > 0; off >>= 1)
        ssum += __shfl_down(ssum, off, 64);
    __shared__ float wsum[4];
    if ((tid & 63) == 0) wsum[tid >> 6] = ssum;
    __syncthreads();
    if (tid == 0)
        partial[flat] = wsum[0] + wsum[1] + wsum[2] + wsum[3];
}

__global__ __launch_bounds__(256) void ssim_final(
        const float* __restrict__ partial, float* __restrict__ out) {
    float s = 0.f;
    for (int i = threadIdx.x; i < NPART; i += 256) s += partial[i];
#pragma unroll
    for (int off = 32; off > 0; off >>= 1)
        s += __shfl_down(s, off, 64);
    __shared__ float wsum[4];
    int lane = threadIdx.x & 63, wid = threadIdx.x >> 6;
    if (lane == 0) wsum[wid] = s;
    __syncthreads();
    if (threadIdx.x == 0) {
        float tot = wsum[0] + wsum[1] + wsum[2] + wsum[3];
        out[0] = 1.0f - tot / (float)NEL;
    }
}

extern "C" void kernel_launch(void* const* d_in, const int* in_sizes, int n_in,
                              void* d_out, int out_size, void* d_ws, size_t ws_size,
                              hipStream_t stream) {
    const float* p = (const float*)d_in[0];
    const float* t = (const float*)d_in[1];
    float* out = (float*)d_out;
    float* partial = (float*)d_ws;   // NPART floats

    G7 gw;
    {
        double s = 0.0, sig = 7.0 / 6.0;
        double g[7];
        for (int i = 0; i < 7; ++i) {
            double d = (double)i - 3.0;
            g[i] = exp(-d * d / (2.0 * sig * sig));
            s += g[i];
        }
        for (int i = 0; i < 7; ++i) gw.g[i] = (float)(g[i] / s);
    }

    ssim_fused<<<NBLK, NTHR, 0, stream>>>(p, t, partial, gw);
    ssim_final<<<1, 256, 0, stream>>>(partial, out);
}

// Round 5
// 129.974 us; speedup vs baseline: 1.0890x; 1.0890x over previous
//
#include <hip/hip_runtime.h>
#include <math.h>

#define DD 160
#define HH 160
#define WW 160
#define NB 2
#define NEL (NB*DD*HH*WW)   // 8,192,000 voxels

#define XT 32               // x outputs per block
#define YT 16               // y outputs per block
#define ZC 16               // z outputs per block
#define NTHR 256
#define NZCH (DD/ZC)        // 10
#define GX (WW/XT)          // 5
#define GY (HH/YT)          // 10
#define NBLK (GX*GY*NB*NZCH)   // 1000 blocks x 4 waves = 4000 waves
#define NPART NBLK

#define HR 22               // halo rows (16 + 6)
#define NJOB (HR*8)         // 176 x-conv jobs (< NTHR)
#define CP 35               // c4 physical pitch in float4 (32 + swizzle)

typedef float v2f __attribute__((ext_vector_type(2)));

struct G7 { float g[7]; };

// Fully fused separable 3D SSIM, v12 = 2 z-slices per barrier interval.
//  * v8-v11 POST-MORTEM: residency pinned at ~2.75 blocks/CU regardless
//    of grid (v9), LDS (v11: 12.8KB -> occupancy DOWN), VGPR; per-wave
//    duty cycle pinned at ~820 issue cy per ~4500 cy slice interval
//    (VALUBusy 50% = 2.75 x 820/4500, consistent across 5 runs). v10
//    killed the vmcnt theory; v11 showed a 2nd barrier per interval is
//    FREE (interval 4600 -> 4580 cy). Conclusion: ~3500 cy/interval is a
//    FIXED per-barrier-interval overhead (barrier skew + LDS latency
//    chains + scheduler dead time), insensitive to work inside.
//  * v12 lever: amortize it. TWO z-slices per barrier pair: B x-convs
//    slices s,s+1 into cA,cB; bar1; prefetch s+2,s+3; C reads both and
//    advances the z-ring twice; bar2 (free per v11). Outputs/interval
//    2x, barriers/slice 0.5x, ring VGPRs reused sequentially.
//  * If fixed-cost theory right: ~2650-3000 cy/slice -> ~40us, VALUBusy
//    65-78%. If flat: theory dead -> wave-autonomous restructure next.
//  * frozen: XCD swizzle, v2f pk-fma, c4 swizzle, z-rings, reg prefetch,
//    epilogue.
__global__ __launch_bounds__(NTHR, 4) void ssim_fused(
        const float* __restrict__ p, const float* __restrict__ t,
        float* __restrict__ partial, G7 gw) {
    const int tid = threadIdx.x;
    const int tx  = tid & 31;            // x output column (phase C)
    const int tyo = tid >> 5;            // 0..7, owns y = 2tyo, 2tyo+1

    // XCD-aware work remap (bijection on [0,1000), 1000 % 8 == 0)
    const int flat = blockIdx.x;
    const int w = (flat & 7) * (NBLK / 8) + (flat >> 3);
    const int bx = w % GX;
    const int by = (w / GX) % GY;
    const int bz = w / (GX * GY);        // 0..19

    const int x0 = bx * XT;
    const int y0 = by * YT;
    const int n  = bz / NZCH;
    const int zs = (bz % NZCH) * ZC;

    __shared__ float4 cA[HR][CP];        // slice s   x-conv (12,320 B)
    __shared__ float4 cB[HR][CP];        // slice s+1 x-conv (12,320 B)

    // z rings: [y-out][slot], slot5 freshest
    v2f r01[2][6], r23[2][6];
#pragma unroll
    for (int yo = 0; yo < 2; ++yo)
#pragma unroll
        for (int j = 0; j < 6; ++j) {
            r01[yo][j] = (v2f)(0.f);
            r23[yo][j] = (v2f)(0.f);
        }

    const float C1v = 1e-4f, C2v = 9e-4f;
    float ssum = 0.f;
    const int hw = HH * WW;
    const float* pv = p + (size_t)n * DD * hw;
    const float* tv = t + (size_t)n * DD * hw;

    // phase-B job decode (tid < 176): row br, x-group bxg
    const int br = tid >> 3;             // 0..21
    const int bxg = tid & 7;             // 0..7
    const int bgy = y0 + br - 3;
    const bool browok = (unsigned)bgy < (unsigned)HH && tid < NJOB;
    const int cbase = x0 + 4 * bxg - 4;  // first loaded column (4-aligned)
    const int pcr = tx + (tx >> 3);      // C-phase swizzled column

    // two prefetch register sets (slice s and s+1 of the NEXT interval)
    float4 pfa0[3], pfb0[3], pfa1[3], pfb1[3];

    auto prefetch = [&](int sx, float4 (&A)[3], float4 (&B)[3]) {
#pragma unroll
        for (int q = 0; q < 3; ++q) {
            A[q] = make_float4(0.f, 0.f, 0.f, 0.f);
            B[q] = make_float4(0.f, 0.f, 0.f, 0.f);
        }
        if (browok && sx >= 0 && sx < DD && sx < zs + ZC + 3) {
            const float* prow = pv + (size_t)sx * hw + bgy * WW;
            const float* trow = tv + (size_t)sx * hw + bgy * WW;
#pragma unroll
            for (int q = 0; q < 3; ++q) {
                int c0 = cbase + 4 * q;
                if ((unsigned)c0 < (unsigned)WW) {
                    A[q] = *(const float4*)(prow + c0);
                    B[q] = *(const float4*)(trow + c0);
                }
            }
        }
    };

    // x-conv of one slice from prefetched regs into one LDS buffer
    auto xconv = [&](const float4 (&Pa)[3], const float4 (&Pb)[3],
                     float4 (*dst)[CP]) {
        v2f s01[4], s23[4];
#pragma unroll
        for (int e = 0; e < 4; ++e) { s01[e] = (v2f)(0.f); s23[e] = (v2f)(0.f); }
#pragma unroll
        for (int q = 0; q < 3; ++q) {
            const float af[4] = {Pa[q].x, Pa[q].y, Pa[q].z, Pa[q].w};
            const float bf[4] = {Pb[q].x, Pb[q].y, Pb[q].z, Pb[q].w};
#pragma unroll
            for (int j = 0; j < 4; ++j) {
                const int i = 4 * q + j;     // loaded position 0..11
                v2f pt; pt[0] = af[j]; pt[1] = bf[j];
                v2f ud; ud[0] = af[j] + bf[j]; ud[1] = af[j] - bf[j];
                v2f qu = ud * ud;
#pragma unroll
                for (int e = 0; e < 4; ++e) {
                    const int k = i - e - 1;  // tap index
                    if (k >= 0 && k < 7) {
                        s01[e] = gw.g[k] * pt + s01[e];
                        s23[e] = gw.g[k] * qu + s23[e];
                    }
                }
            }
        }
#pragma unroll
        for (int e = 0; e < 4; ++e) {
            int c = 4 * bxg + e;
            dst[br][c + (c >> 3)] =
                make_float4(s01[e][0], s01[e][1], s23[e][0], s23[e][1]);
        }
    };

    // y-conv + z-ring advance (+emit) for one slice
    auto yring = [&](int ss, bool vv, const float4 (*src)[CP]) {
        v2f m01[2], m23[2];
#pragma unroll
        for (int yo = 0; yo < 2; ++yo) {
            m01[yo] = (v2f)(0.f);
            m23[yo] = (v2f)(0.f);
        }
        if (vv) {
#pragma unroll
            for (int r8 = 0; r8 < 8; ++r8) {
                float4 v = src[2 * tyo + r8][pcr];
                v2f v01; v01[0] = v.x; v01[1] = v.y;
                v2f v23; v23[0] = v.z; v23[1] = v.w;
                if (r8 < 7) {
                    float w2 = gw.g[r8];
                    m01[0] = w2 * v01 + m01[0];
                    m23[0] = w2 * v23 + m23[0];
                }
                if (r8 > 0) {
                    float w2 = gw.g[r8 - 1];
                    m01[1] = w2 * v01 + m01[1];
                    m23[1] = w2 * v23 + m23[1];
                }
            }
        }
        // ring shift runs unconditionally (zero-padding semantics)
#pragma unroll
        for (int yo = 0; yo < 2; ++yo) {
            v2f v01 = m01[yo], v23 = m23[yo];
            v2f cons01 = gw.g[6] * v01 + r01[yo][0];
            v2f cons23 = gw.g[6] * v23 + r23[yo][0];
#pragma unroll
            for (int j = 0; j < 5; ++j) {
                r01[yo][j] = gw.g[5 - j] * v01 + r01[yo][j + 1];
                r23[yo][j] = gw.g[5 - j] * v23 + r23[yo][j + 1];
            }
            r01[yo][5] = gw.g[0] * v01;
            r23[yo][5] = gw.g[0] * v23;

            if (ss >= zs + 3) {   // output z = ss-3
                float mu1 = cons01[0], mu2 = cons01[1];
                float Eu  = cons23[0], Ew  = cons23[1];
                float mu12 = mu1 * mu2, mu1sq = mu1 * mu1, mu2sq = mu2 * mu2;
                float sumsq = 0.5f  * (Eu + Ew) - mu1sq - mu2sq; // s1+s2
                float s12   = 0.25f * (Eu - Ew) - mu12;          // sigma12
                float num = (2.f * mu12 + C1v) * (2.f * s12 + C2v);
                float den = (mu1sq + mu2sq + C1v) * (sumsq + C2v);
                ssum += num * __builtin_amdgcn_rcpf(den);
            }
        }
    };

    // prologue: fill both prefetch sets (slices zs-3, zs-2)
    prefetch(zs - 3, pfa0, pfb0);
    prefetch(zs - 2, pfa1, pfb1);

    // 22 slices = 11 double-slice barrier intervals
    for (int s = zs - 3; s < zs + ZC + 3; s += 2) {
        const bool v0 = (s >= 0) && (s < DD);          // block-uniform
        const bool v1 = (s + 1 >= 0) && (s + 1 < DD);  // block-uniform

        if (v0 || v1) {
            // ---- B: x-conv for both slices of this interval ----
            if (tid < NJOB) {
                if (v0) xconv(pfa0, pfb0, cA);
                if (v1) xconv(pfa1, pfb1, cB);
            }
            __syncthreads();   // bar1: B-writes visible
        }

        // ---- issue next interval's global loads (overlap C + rings) ----
        prefetch(s + 2, pfa0, pfb0);
        prefetch(s + 3, pfa1, pfb1);

        // ---- C + z-ring, twice ----
        yring(s,     v0, cA);
        yring(s + 1, v1, cB);

        if (v0 || v1)
            __syncthreads();   // bar2: C-reads done -> next B may overwrite
    }

    // ---- block reduction (4 waves) ----
#pragma unroll
    for (int off = 32; off > 0; off >>= 1)
        ssum += __shfl_down(ssum, off, 64);
    __shared__ float wsum[4];
    if ((tid & 63) == 0) wsum[tid >> 6] = ssum;
    __syncthreads();
    if (tid == 0)
        partial[flat] = wsum[0] + wsum[1] + wsum[2] + wsum[3];
}

__global__ __launch_bounds__(256) void ssim_final(
        const float* __restrict__ partial, float* __restrict__ out) {
    float s = 0.f;
    for (int i = threadIdx.x; i < NPART; i += 256) s += partial[i];
#pragma unroll
    for (int off = 32; off > 0; off >>= 1)
        s += __shfl_down(s, off, 64);
    __shared__ float wsum[4];
    int lane = threadIdx.x & 63, wid = threadIdx.x >> 6;
    if (lane == 0) wsum[wid] = s;
    __syncthreads();
    if (threadIdx.x == 0) {
        float tot = wsum[0] + wsum[1] + wsum[2] + wsum[3];
        out[0] = 1.0f - tot / (float)NEL;
    }
}

extern "C" void kernel_launch(void* const* d_in, const int* in_sizes, int n_in,
                              void* d_out, int out_size, void* d_ws, size_t ws_size,
                              hipStream_t stream) {
    const float* p = (const float*)d_in[0];
    const float* t = (const float*)d_in[1];
    float* out = (float*)d_out;
    float* partial = (float*)d_ws;   // NPART floats

    G7 gw;
    {
        double s = 0.0, sig = 7.0 / 6.0;
        double g[7];
        for (int i = 0; i < 7; ++i) {
            double d = (double)i - 3.0;
            g[i] = exp(-d * d / (2.0 * sig * sig));
            s += g[i];
        }
        for (int i = 0; i < 7; ++i) gw.g[i] = (float)(g[i] / s);
    }

    ssim_fused<<<NBLK, NTHR, 0, stream>>>(p, t, partial, gw);
    ssim_final<<<1, 256, 0, stream>>>(partial, out);
}

// Round 6
// 129.205 us; speedup vs baseline: 1.0955x; 1.0059x over previous
//
#include <hip/hip_runtime.h>
#include <math.h>

#define DD 160
#define HH 160
#define WW 160
#define NB 2
#define NEL (NB*DD*HH*WW)   // 8,192,000 voxels

#define XT 32               // x outputs per block
#define YT 16               // y outputs per block
#define ZC 16               // z outputs per block
#define NTHR 256
#define NZCH (DD/ZC)        // 10
#define GX (WW/XT)          // 5
#define GY (HH/YT)          // 10
#define NBLK (GX*GY*NB*NZCH)   // 1000 blocks x 4 waves = 4000 waves
#define NPART NBLK

#define HR 22               // halo rows (16 + 6)
#define NJOB (HR*8)         // 176 x-conv jobs (< NTHR)
#define CP 35               // c4 physical pitch in float4 (32 + swizzle)

typedef float v2f __attribute__((ext_vector_type(2)));

struct G7 { float g[7]; };

// Fully fused separable 3D SSIM, v13 = v7 + instruction diet.
//  * v8-v12 POST-MORTEM: every structural lever is falsified -- grid
//    (v9), prefetch depth (v10), LDS footprint (v11), barrier count
//    (v11/v12). The one robust correlation: dur tracks ISSUED
//    INSTRUCTION VOLUME (v9 +27% work -> +18% dur; v7=v10=v11=v12 same
//    instrs -> same 58-60us; VALUBusy pinned ~50% equilibrium).
//    Measured ~400 wave-instr/wave/slice vs ~150 useful math -> ~2.5x
//    overhead: per-slice zeroing movs, 64-bit addr rebuilds, swizzle
//    index recompute, mask re-evaluation.
//  * v13 diet (structure untouched from v7):
//    1. zero pfa/pfb ONCE pre-loop (invalid lanes keep zeros forever --
//       same padding semantics); -24 movs/slice/thread.
//    2. per-thread 32-bit load offset qoff=bgy*WW+c0 hoisted; per-slice
//       base pv+sx*hw is uniform (SALU) -> saddr+voff loads, no vector
//       64-bit addr chains.
//    3. per-q validity masks hoisted; x-interior blocks (bx 1..3,
//       block-uniform) take a single-branch path for all 6 loads.
//    4. LDS write index c+(c>>3) == 4*bxg+(bxg>>1)+e (no 8-crossing for
//       e<4): base hoisted, e folds into write offsets.
//  * Prediction: dur ~50-53us if dur∝instrs; flat -> theory dead ->
//    radical restructure next.
__global__ __launch_bounds__(NTHR, 4) void ssim_fused(
        const float* __restrict__ p, const float* __restrict__ t,
        float* __restrict__ partial, G7 gw) {
    const int tid = threadIdx.x;
    const int tx  = tid & 31;            // x output column (phase C)
    const int tyo = tid >> 5;            // 0..7, owns y = 2tyo, 2tyo+1

    // XCD-aware work remap (bijection on [0,1000), 1000 % 8 == 0)
    const int flat = blockIdx.x;
    const int w = (flat & 7) * (NBLK / 8) + (flat >> 3);
    const int bx = w % GX;
    const int by = (w / GX) % GY;
    const int bz = w / (GX * GY);        // 0..19

    const int x0 = bx * XT;
    const int y0 = by * YT;
    const int n  = bz / NZCH;
    const int zs = (bz % NZCH) * ZC;

    __shared__ float4 c4[2][HR][CP];

    // z rings: [y-out][slot], slot5 freshest
    v2f r01[2][6], r23[2][6];
#pragma unroll
    for (int yo = 0; yo < 2; ++yo)
#pragma unroll
        for (int j = 0; j < 6; ++j) {
            r01[yo][j] = (v2f)(0.f);
            r23[yo][j] = (v2f)(0.f);
        }

    const float C1v = 1e-4f, C2v = 9e-4f;
    float ssum = 0.f;
    const int hw = HH * WW;
    const float* pv = p + (size_t)n * DD * hw;
    const float* tv = t + (size_t)n * DD * hw;

    // phase-B job decode (tid < 176): row br, x-group bxg
    const int br = tid >> 3;             // 0..21
    const int bxg = tid & 7;             // 0..7
    const int bgy = y0 + br - 3;
    const bool browok = (unsigned)bgy < (unsigned)HH && tid < NJOB;
    const int cbase = x0 + 4 * bxg - 4;  // first loaded column (4-aligned)
    const int pcr = tx + (tx >> 3);      // C-phase swizzled column

    // ---- hoisted per-thread load geometry (slice-invariant) ----
    const int rowoff = bgy * WW;         // garbage if !browok (never used)
    bool qv[3]; int qoff[3];
#pragma unroll
    for (int q = 0; q < 3; ++q) {
        const int c0 = cbase + 4 * q;
        qv[q] = browok && ((unsigned)c0 < (unsigned)WW);
        qoff[q] = rowoff + c0;
    }
    // interior-x blocks: all columns in range -> qv[q] == browok for all q
    const bool interior_x = (bx >= 1) && (bx <= GX - 2);   // block-uniform
    // hoisted LDS write base index: c+(c>>3) with c=4*bxg+e, e<4
    const int cws = 4 * bxg + (bxg >> 1);

    // prefetch registers: zeroed ONCE; invalid lanes stay zero forever
    float4 pfa[3], pfb[3];
#pragma unroll
    for (int q = 0; q < 3; ++q) {
        pfa[q] = make_float4(0.f, 0.f, 0.f, 0.f);
        pfb[q] = make_float4(0.f, 0.f, 0.f, 0.f);
    }

    auto prefetch = [&](int sx) {
        if (sx >= 0 && sx < DD && sx < zs + ZC + 3) {   // block-uniform
            const float* ps = pv + (size_t)sx * hw;     // uniform base
            const float* ts = tv + (size_t)sx * hw;
            if (interior_x) {
                if (browok) {
#pragma unroll
                    for (int q = 0; q < 3; ++q) {
                        pfa[q] = *(const float4*)(ps + qoff[q]);
                        pfb[q] = *(const float4*)(ts + qoff[q]);
                    }
                }
            } else {
#pragma unroll
                for (int q = 0; q < 3; ++q) {
                    if (qv[q]) {
                        pfa[q] = *(const float4*)(ps + qoff[q]);
                        pfb[q] = *(const float4*)(ts + qoff[q]);
                    }
                }
            }
        }
    };

    prefetch(zs - 3);

    for (int s = zs - 3; s < zs + ZC + 3; ++s) {
        const int par = s & 1;
        const bool valid = (s >= 0) && (s < DD);   // block-uniform

        if (valid) {
            // ---- B: x-conv from prefetched registers ----
            if (tid < NJOB) {
                v2f s01[4], s23[4];
#pragma unroll
                for (int e = 0; e < 4; ++e) { s01[e] = (v2f)(0.f); s23[e] = (v2f)(0.f); }
#pragma unroll
                for (int q = 0; q < 3; ++q) {
                    const float af[4] = {pfa[q].x, pfa[q].y, pfa[q].z, pfa[q].w};
                    const float bf[4] = {pfb[q].x, pfb[q].y, pfb[q].z, pfb[q].w};
#pragma unroll
                    for (int j = 0; j < 4; ++j) {
                        const int i = 4 * q + j;     // loaded position 0..11
                        v2f pt; pt[0] = af[j]; pt[1] = bf[j];
                        v2f ud; ud[0] = af[j] + bf[j]; ud[1] = af[j] - bf[j];
                        v2f qu = ud * ud;
#pragma unroll
                        for (int e = 0; e < 4; ++e) {
                            const int k = i - e - 1;  // tap index
                            if (k >= 0 && k < 7) {
                                s01[e] = gw.g[k] * pt + s01[e];
                                s23[e] = gw.g[k] * qu + s23[e];
                            }
                        }
                    }
                }
#pragma unroll
                for (int e = 0; e < 4; ++e) {
                    c4[par][br][cws + e] =
                        make_float4(s01[e][0], s01[e][1], s23[e][0], s23[e][1]);
                }
            }
            __syncthreads();   // block-uniform (valid is uniform)
        }

        // ---- issue next slice's global loads NOW (overlap C + ring) ----
        prefetch(s + 1);

        v2f m01[2], m23[2];
#pragma unroll
        for (int yo = 0; yo < 2; ++yo) {
            m01[yo] = (v2f)(0.f);
            m23[yo] = (v2f)(0.f);
        }

        if (valid) {
            // ---- C: y-conv, stream 8 rows for both y-outputs ----
#pragma unroll
            for (int r8 = 0; r8 < 8; ++r8) {
                float4 v = c4[par][2 * tyo + r8][pcr];
                v2f v01; v01[0] = v.x; v01[1] = v.y;
                v2f v23; v23[0] = v.z; v23[1] = v.w;
                if (r8 < 7) {
                    float w2 = gw.g[r8];
                    m01[0] = w2 * v01 + m01[0];
                    m23[0] = w2 * v23 + m23[0];
                }
                if (r8 > 0) {
                    float w2 = gw.g[r8 - 1];
                    m01[1] = w2 * v01 + m01[1];
                    m23[1] = w2 * v23 + m23[1];
                }
            }
            // no trailing barrier: dbuf; WAR fenced by next slice's barrier.
        }

        // ---- z rings: consume slot0, shift+FMA, refill ----
#pragma unroll
        for (int yo = 0; yo < 2; ++yo) {
            v2f v01 = m01[yo], v23 = m23[yo];
            v2f cons01 = gw.g[6] * v01 + r01[yo][0];
            v2f cons23 = gw.g[6] * v23 + r23[yo][0];
#pragma unroll
            for (int j = 0; j < 5; ++j) {
                r01[yo][j] = gw.g[5 - j] * v01 + r01[yo][j + 1];
                r23[yo][j] = gw.g[5 - j] * v23 + r23[yo][j + 1];
            }
            r01[yo][5] = gw.g[0] * v01;
            r23[yo][5] = gw.g[0] * v23;

            if (s >= zs + 3) {   // output z = s-3
                float mu1 = cons01[0], mu2 = cons01[1];
                float Eu  = cons23[0], Ew  = cons23[1];
                float mu12 = mu1 * mu2, mu1sq = mu1 * mu1, mu2sq = mu2 * mu2;
                float sumsq = 0.5f  * (Eu + Ew) - mu1sq - mu2sq; // s1+s2
                float s12   = 0.25f * (Eu - Ew) - mu12;          // sigma12
                float num = (2.f * mu12 + C1v) * (2.f * s12 + C2v);
                float den = (mu1sq + mu2sq + C1v) * (sumsq + C2v);
                ssum += num * __builtin_amdgcn_rcpf(den);
            }
        }
    }

    // ---- block reduction (4 waves) ----
#pragma unroll
    for (int off = 32; off > 0; off >>= 1)
        ssum += __shfl_down(ssum, off, 64);
    __shared__ float wsum[4];
    if ((tid & 63) == 0) wsum[tid >> 6] = ssum;
    __syncthreads();
    if (tid == 0)
        partial[flat] = wsum[0] + wsum[1] + wsum[2] + wsum[3];
}

__global__ __launch_bounds__(256) void ssim_final(
        const float* __restrict__ partial, float* __restrict__ out) {
    float s = 0.f;
    for (int i = threadIdx.x; i < NPART; i += 256) s += partial[i];
#pragma unroll
    for (int off = 32; off > 0; off >>= 1)
        s += __shfl_down(s, off, 64);
    __shared__ float wsum[4];
    int lane = threadIdx.x & 63, wid = threadIdx.x >> 6;
    if (lane == 0) wsum[wid] = s;
    __syncthreads();
    if (threadIdx.x == 0) {
        float tot = wsum[0] + wsum[1] + wsum[2] + wsum[3];
        out[0] = 1.0f - tot / (float)NEL;
    }
}

extern "C" void kernel_launch(void* const* d_in, const int* in_sizes, int n_in,
                              void* d_out, int out_size, void* d_ws, size_t ws_size,
                              hipStream_t stream) {
    const float* p = (const float*)d_in[0];
    const float* t = (const float*)d_in[1];
    float* out = (float*)d_out;
    float* partial = (float*)d_ws;   // NPART floats

    G7 gw;
    {
        double s = 0.0, sig = 7.0 / 6.0;
        double g[7];
        for (int i = 0; i < 7; ++i) {
            double d = (double)i - 3.0;
            g[i] = exp(-d * d / (2.0 * sig * sig));
            s += g[i];
        }
        for (int i = 0; i < 7; ++i) gw.g[i] = (float)(g[i] / s);
    }

    ssim_fused<<<NBLK, NTHR, 0, stream>>>(p, t, partial, gw);
    ssim_final<<<1, 256, 0, stream>>>(partial, out);
}